// Round 13
// baseline (720.105 us; speedup 1.0000x reference)
//
#include <hip/hip_runtime.h>
#include <hip/hip_bf16.h>
#include <math.h>

#define T_TOK 1024
#define H_DIM 2048
#define I_DIM 768
#define E_NUM 32
#define K_TOP 8
#define BK 32
#define GRID_P 1024

typedef __bf16 bf16x8 __attribute__((ext_vector_type(8)));
typedef float  f32x4  __attribute__((ext_vector_type(4)));

__device__ __forceinline__ bf16x8 cvt2_bf16(const f32x4 a, const f32x4 b) {
    bf16x8 r;
    r[0] = (__bf16)a[0]; r[1] = (__bf16)a[1]; r[2] = (__bf16)a[2]; r[3] = (__bf16)a[3];
    r[4] = (__bf16)b[0]; r[5] = (__bf16)b[1]; r[6] = (__bf16)b[2]; r[7] = (__bf16)b[3];
    return r;
}

// LDS fragment-order layout (128 rows x 32 k bf16): element (r,k) at
// (r>>4)*512 + (k>>3)*128 + (r&15)*8 + (k&7). Wave fragment read =
// subtile*512 + lane*8 (16B/lane, linear).
__device__ __forceinline__ int frag_off(int r, int kgrp8) {
    return (r >> 4) * 512 + kgrp8 * 128 + (r & 15) * 8;
}

// ---------------- Router: logits -> top-8 weights; also emits xb (bf16 x) ---
__global__ __launch_bounds__(256) void router_kernel(
    const float* __restrict__ x, const float* __restrict__ gw,
    float* __restrict__ wdense, unsigned int* __restrict__ masks,
    __bf16* __restrict__ xb)
{
    const int t = blockIdx.x;
    const int tid = threadIdx.x;
    __shared__ float part[256];
    __shared__ float logits[E_NUM];

    // fold of cvtx: this block owns row t; write bf16 copy
    {
        const float* xr2 = x + (size_t)t * H_DIM + tid * 8;
        const f32x4 a = *(const f32x4*)(xr2);
        const f32x4 b = *(const f32x4*)(xr2 + 4);
        *(bf16x8*)(xb + (size_t)t * H_DIM + tid * 8) = cvt2_bf16(a, b);
    }

    const int e = tid & 31;
    const int chunk = tid >> 5;
    const float* xr = x + (size_t)t * H_DIM;
    const float* gr = gw + (size_t)e * H_DIM;
    const int base = chunk * (H_DIM / 8);
    float s = 0.f;
    for (int h = 0; h < H_DIM / 8; h += 4) {
        const f32x4 xv = *reinterpret_cast<const f32x4*>(xr + base + h);
        const f32x4 gv = *reinterpret_cast<const f32x4*>(gr + base + h);
        s += xv[0]*gv[0] + xv[1]*gv[1] + xv[2]*gv[2] + xv[3]*gv[3];
    }
    part[tid] = s;
    __syncthreads();
    if (tid < E_NUM) {
        float tot = 0.f;
        for (int c = 0; c < 8; ++c) tot += part[c * 32 + tid];
        logits[tid] = tot;
    }
    __syncthreads();
    if (tid == 0) {
        float l[E_NUM];
        for (int i = 0; i < E_NUM; ++i) {
            l[i] = logits[i];
            wdense[(size_t)t * E_NUM + i] = 0.f;
        }
        unsigned mask = 0;
        int   idx[K_TOP];
        float lv[K_TOP];
        for (int k = 0; k < K_TOP; ++k) {
            float best = -1e30f; int bi = 0;
            for (int i = 0; i < E_NUM; ++i)
                if (!((mask >> i) & 1u) && l[i] > best) { best = l[i]; bi = i; }
            mask |= (1u << bi); idx[k] = bi; lv[k] = best;
        }
        const float m = lv[0];
        float den = 0.f;
        for (int k = 0; k < K_TOP; ++k) den += expf(lv[k] - m);
        for (int k = 0; k < K_TOP; ++k)
            wdense[(size_t)t * E_NUM + idx[k]] = expf(lv[k] - m) / den;
        masks[t] = mask;
    }
}

// ---------------- Build compacted per-expert token lists --------------------
__global__ __launch_bounds__(256) void count_kernel(
    const unsigned int* __restrict__ masks, int* __restrict__ cnt)
{
    const int e = blockIdx.x;
    const int tid = threadIdx.x;
    int c = 0;
    for (int t = tid; t < T_TOK; t += 256) c += (masks[t] >> e) & 1u;
    __shared__ int red[256];
    red[tid] = c; __syncthreads();
    for (int s = 128; s > 0; s >>= 1) {
        if (tid < s) red[tid] += red[tid + s];
        __syncthreads();
    }
    if (tid == 0) cnt[e] = red[0];
}

// scan + live-tile table: tbl[0]=ntiles, tbl[1+i] = (e<<8)|zt  (128-token tiles)
__global__ void scan_kernel(const int* __restrict__ cnt, int* __restrict__ off,
                            int* __restrict__ tbl)
{
    if (threadIdx.x == 0 && blockIdx.x == 0) {
        int r = 0, nt = 0;
        for (int e = 0; e < E_NUM; ++e) {
            off[e] = r;
            const int c = cnt[e];
            r += c;
            const int t = (c + 127) >> 7;
            for (int z = 0; z < t; ++z) tbl[1 + nt++] = (e << 8) | z;
        }
        tbl[0] = nt;
    }
}

// fill: compacted token list + weights + deterministic slot map
// posl[t*8 + slot] = compacted position, slot = #selected experts of t below e.
__global__ __launch_bounds__(256) void fill_kernel(
    const unsigned int* __restrict__ masks, const float* __restrict__ wdense,
    const int* __restrict__ off, int* __restrict__ tok, float* __restrict__ wgt,
    int* __restrict__ posl)
{
    const int e = blockIdx.x;
    const int tid = threadIdx.x;
    const int PER = T_TOK / 256;
    int sel[PER]; int c = 0;
    for (int i = 0; i < PER; ++i) {
        const int t = tid * PER + i;
        sel[i] = (masks[t] >> e) & 1u;
        c += sel[i];
    }
    __shared__ int s[256];
    s[tid] = c; __syncthreads();
    if (tid == 0) {
        int r = 0;
        for (int j = 0; j < 256; ++j) { int v = s[j]; s[j] = r; r += v; }
    }
    __syncthreads();
    int pos = off[e] + s[tid];
    for (int i = 0; i < PER; ++i) {
        if (sel[i]) {
            const int t = tid * PER + i;
            tok[pos] = t;
            wgt[pos] = wdense[(size_t)t * E_NUM + e];
            const int slot = __popc(masks[t] & ((1u << e) - 1u));
            posl[t * K_TOP + slot] = pos;
            pos++;
        }
    }
}

// Phase macro (round-10 verified): prefetch step scur+2 into regset P, MFMA
// from buf P, write regset Q (=step scur+1) into buf Q. lgkmcnt(0)+raw
// barrier only; global loads stay in flight across the barrier.
#define GEMM_PHASE(P, Q)                                                       \
  {                                                                            \
    if (scur + 2 < NS) {                                                       \
      const int kk = (scur + 2) * BK;                                          \
      pa##P##_0 = *(const bf16x8*)(ap + kk);                                   \
      pa##P##_1 = *(const bf16x8*)(ap + kk + 8);                               \
      pb##P##_0 = *(const f32x4*)(wp + kk);                                    \
      pb##P##_1 = *(const f32x4*)(wp + kk + 4);                                \
      pb##P##_2 = *(const f32x4*)(wp + kk + 8);                                \
      pb##P##_3 = *(const f32x4*)(wp + kk + 12);                               \
    }                                                                          \
    bf16x8 af[4], bfr[4];                                                      \
    _Pragma("unroll")                                                          \
    for (int m = 0; m < 4; ++m)                                                \
      af[m] = *(const bf16x8*)&As[P][((wm >> 4) + m) * 512 + lane * 8];        \
    _Pragma("unroll")                                                          \
    for (int n = 0; n < 4; ++n)                                                \
      bfr[n] = *(const bf16x8*)&Bs[P][(wn * 4 + n) * 512 + lane * 8];          \
    _Pragma("unroll")                                                          \
    for (int m = 0; m < 4; ++m)                                                \
      _Pragma("unroll")                                                        \
      for (int n = 0; n < 4; ++n)                                              \
        acc[m][n] = __builtin_amdgcn_mfma_f32_16x16x32_bf16(af[m], bfr[n],     \
                                                            acc[m][n], 0,0,0); \
    if (scur + 1 < NS) {                                                       \
      *(bf16x8*)&As[Q][wo]       = pa##Q##_0;                                  \
      *(bf16x8*)&As[Q][wo + 128] = pa##Q##_1;                                  \
      *(bf16x8*)&Bs[Q][wo]       = cvt2_bf16(pb##Q##_0, pb##Q##_1);            \
      *(bf16x8*)&Bs[Q][wo + 128] = cvt2_bf16(pb##Q##_2, pb##Q##_3);            \
    }                                                                          \
    asm volatile("s_waitcnt lgkmcnt(0)" ::: "memory");                         \
    __builtin_amdgcn_s_barrier();                                              \
    ++scur;                                                                    \
  }

#define GEMM_PROLOGUE()                                                        \
    pa0_0 = *(const bf16x8*)(ap);                                              \
    pa0_1 = *(const bf16x8*)(ap + 8);                                          \
    pb0_0 = *(const f32x4*)(wp);                                               \
    pb0_1 = *(const f32x4*)(wp + 4);                                           \
    pb0_2 = *(const f32x4*)(wp + 8);                                           \
    pb0_3 = *(const f32x4*)(wp + 12);                                          \
    pa1_0 = *(const bf16x8*)(ap + BK);                                         \
    pa1_1 = *(const bf16x8*)(ap + BK + 8);                                     \
    pb1_0 = *(const f32x4*)(wp + BK);                                          \
    pb1_1 = *(const f32x4*)(wp + BK + 4);                                      \
    pb1_2 = *(const f32x4*)(wp + BK + 8);                                      \
    pb1_3 = *(const f32x4*)(wp + BK + 12);                                     \
    *(bf16x8*)&As[0][wo]       = pa0_0;                                        \
    *(bf16x8*)&As[0][wo + 128] = pa0_1;                                        \
    *(bf16x8*)&Bs[0][wo]       = cvt2_bf16(pb0_0, pb0_1);                      \
    *(bf16x8*)&Bs[0][wo + 128] = cvt2_bf16(pb0_2, pb0_3);                      \
    asm volatile("s_waitcnt lgkmcnt(0)" ::: "memory");                         \
    __builtin_amdgcn_s_barrier();

// ---------------- GEMM1: act = silu(x @ w1^T) * (x @ w3^T) ------------------
// Persistent, work w = tile*12 + nidx. Tile: 128 tok x 128 Brows
// ([0:32)=gate lo, [32:64)=up lo, [64:96)=gate hi, [96:128)=up hi).
// Wave (2Mx2N): 64 tok x 64 Brows -> acc[4][4]; n=0,1 gate, n=2,3 up.
// (256,4): 4 blocks/CU (LDS 4x32KB=128KB, VGPR ~84 < cap 128) — convoy A/B.
__global__ __launch_bounds__(256, 4) void gemm1_kernel(
    const __bf16* __restrict__ xb, const float* __restrict__ w13,
    const int* __restrict__ tok, const int* __restrict__ cnt,
    const int* __restrict__ off, const int* __restrict__ tbl,
    unsigned short* __restrict__ act)
{
    __shared__ __bf16 As[2][4096];
    __shared__ __bf16 Bs[2][4096];
    const int tid  = threadIdx.x;
    const int wid  = tid >> 6;
    const int lane = tid & 63;
    const int wm = (wid >> 1) * 64;
    const int wn = (wid & 1);
    const int lrow = lane & 15;
    const int sr = tid >> 1;
    const int kh = tid & 1;
    const int wo = frag_off(sr, kh * 2);
    const int NS = H_DIM / BK;   // 64

    const int W = tbl[0] * 12;
    for (int w = blockIdx.x; w < W; w += gridDim.x) {
        const int ti   = w / 12;
        const int nidx = w - ti * 12;
        const int ez = tbl[1 + ti];
        const int e  = ez >> 8;
        const int m0 = (ez & 255) * 128;
        const int c  = cnt[e];
        const int o  = off[e];
        const int n0 = nidx * 64;

        int rA = m0 + sr; rA = rA < c ? rA : c - 1;
        const __bf16* ap = xb + (size_t)tok[o + rA] * H_DIM + kh * 16;
        const int grp = sr >> 5;
        const int wrow = (grp & 1) * I_DIM + n0 + (grp >> 1) * 32 + (sr & 31);
        const float* wp = w13 + (size_t)e * (2 * I_DIM) * H_DIM
                              + (size_t)wrow * H_DIM + kh * 16;

        bf16x8 pa0_0, pa0_1, pa1_0, pa1_1;
        f32x4  pb0_0, pb0_1, pb0_2, pb0_3, pb1_0, pb1_1, pb1_2, pb1_3;
        f32x4  acc[4][4] = {};

        GEMM_PROLOGUE()

        int scur = 0;
        for (int it = 0; it < NS; it += 2) {
            GEMM_PHASE(0, 1)
            GEMM_PHASE(1, 0)
        }

        // epilogue: n=0,1 gate, n=2,3 up; icol = n0 + wn*32 + n*16 + lrow
#pragma unroll
        for (int m = 0; m < 4; ++m)
#pragma unroll
            for (int n = 0; n < 2; ++n)
#pragma unroll
                for (int i = 0; i < 4; ++i) {
                    const int row = m0 + wm + m * 16 + (lane >> 4) * 4 + i;
                    if (row < c) {
                        const int icol = n0 + wn * 32 + n * 16 + lrow;
                        const float g = acc[m][n][i];
                        const float u = acc[m][n + 2][i];
                        const float a = (g / (1.f + expf(-g))) * u;
                        act[(size_t)(o + row) * I_DIM + icol] =
                            __builtin_bit_cast(unsigned short, (__bf16)a);
                    }
                }
    }
}

// ---------------- GEMM2: ybuf[o+row] = wgt * (act @ w2^T) (NO atomics) ------
// Persistent, work w = tile*16 + nidx. Tile: 128 tok x 128 H-cols.
__global__ __launch_bounds__(256, 4) void gemm2_kernel(
    const unsigned short* __restrict__ act, const float* __restrict__ w2,
    const int* __restrict__ tok, const float* __restrict__ wgt,
    const int* __restrict__ cnt, const int* __restrict__ off,
    const int* __restrict__ tbl, float* __restrict__ ybuf)
{
    __shared__ __bf16 As[2][4096];
    __shared__ __bf16 Bs[2][4096];
    const int tid  = threadIdx.x;
    const int wid  = tid >> 6;
    const int lane = tid & 63;
    const int wm = (wid >> 1) * 64;
    const int wn = (wid & 1);
    const int lrow = lane & 15;
    const int sr = tid >> 1;
    const int kh = tid & 1;
    const int wo = frag_off(sr, kh * 2);
    const int NS = I_DIM / BK;   // 24

    const int W = tbl[0] * 16;
    for (int w = blockIdx.x; w < W; w += gridDim.x) {
        const int ti   = w >> 4;
        const int nidx = w & 15;
        const int ez = tbl[1 + ti];
        const int e  = ez >> 8;
        const int m0 = (ez & 255) * 128;
        const int c  = cnt[e];
        const int o  = off[e];
        const int n0 = nidx * 128;

        int rA = m0 + sr; rA = rA < c ? rA : c - 1;
        const __bf16* ap = (const __bf16*)act + (size_t)(o + rA) * I_DIM + kh * 16;
        const float* wp = w2 + (size_t)e * H_DIM * I_DIM
                             + (size_t)(n0 + sr) * I_DIM + kh * 16;

        bf16x8 pa0_0, pa0_1, pa1_0, pa1_1;
        f32x4  pb0_0, pb0_1, pb0_2, pb0_3, pb1_0, pb1_1, pb1_2, pb1_3;
        f32x4  acc[4][4] = {};

        GEMM_PROLOGUE()

        int scur = 0;
        for (int it = 0; it < NS; it += 2) {
            GEMM_PHASE(0, 1)
            GEMM_PHASE(1, 0)
        }

        // epilogue: weighted partial rows, plain coalesced stores (no RMW)
#pragma unroll
        for (int m = 0; m < 4; ++m)
#pragma unroll
            for (int i = 0; i < 4; ++i) {
                const int row = m0 + wm + m * 16 + (lane >> 4) * 4 + i;
                if (row < c) {
                    const float wv = wgt[o + row];
                    float* yr = ybuf + (size_t)(o + row) * H_DIM + n0 + wn * 64 + lrow;
#pragma unroll
                    for (int n = 0; n < 4; ++n)
                        yr[n * 16] = wv * acc[m][n][i];
                }
            }
    }
}

// ---------------- Combine: out[t] = sum_s ybuf[posl[t*8+s]] -----------------
__global__ __launch_bounds__(256) void combine_kernel(
    const float* __restrict__ ybuf, const int* __restrict__ posl,
    float* __restrict__ out)
{
    const int t = blockIdx.x;
    int p[K_TOP];
#pragma unroll
    for (int s = 0; s < K_TOP; ++s) p[s] = posl[t * K_TOP + s];
    const int h0 = threadIdx.x * 4;
#pragma unroll
    for (int hh = h0; hh < H_DIM; hh += 1024) {
        f32x4 a = {0.f, 0.f, 0.f, 0.f};
#pragma unroll
        for (int s = 0; s < K_TOP; ++s) {
            const f32x4 v = *(const f32x4*)(ybuf + (size_t)p[s] * H_DIM + hh);
            a[0] += v[0]; a[1] += v[1]; a[2] += v[2]; a[3] += v[3];
        }
        *(f32x4*)(out + (size_t)t * H_DIM + hh) = a;
    }
}

// ---------------- Launch ----------------------------------------------------
extern "C" void kernel_launch(void* const* d_in, const int* in_sizes, int n_in,
                              void* d_out, int out_size, void* d_ws, size_t ws_size,
                              hipStream_t stream)
{
    const float* x   = (const float*)d_in[0];
    const float* gw  = (const float*)d_in[1];
    const float* w13 = (const float*)d_in[2];
    const float* w2  = (const float*)d_in[3];
    float* out = (float*)d_out;

    char* ws = (char*)d_ws;
    float*          wdense = (float*)(ws + 0x00000);
    unsigned int*   masks  = (unsigned int*)(ws + 0x20000);
    int*            cnt    = (int*)(ws + 0x21000);
    int*            off    = (int*)(ws + 0x21800);
    int*            tbl    = (int*)(ws + 0x22000);
    int*            tok    = (int*)(ws + 0x23000);
    float*          wgt    = (float*)(ws + 0x2B000);
    unsigned short* act    = (unsigned short*)(ws + 0x33000);    // 12.6 MB
    __bf16*         xb     = (__bf16*)(ws + 0xC40000);           // 4 MB
    int*            posl   = (int*)(ws + 0x1040000);             // 32 KB
    float*          ybuf   = (float*)(ws + 0x1100000);           // 67 MB

    router_kernel<<<T_TOK, 256, 0, stream>>>(x, gw, wdense, masks, xb);
    count_kernel<<<E_NUM, 256, 0, stream>>>(masks, cnt);
    scan_kernel<<<1, 64, 0, stream>>>(cnt, off, tbl);
    fill_kernel<<<E_NUM, 256, 0, stream>>>(masks, wdense, off, tok, wgt, posl);
    gemm1_kernel<<<GRID_P, 256, 0, stream>>>(xb, w13, tok, cnt, off, tbl, act);
    gemm2_kernel<<<GRID_P, 256, 0, stream>>>(act, w2, tok, wgt, cnt, off, tbl, ybuf);
    combine_kernel<<<T_TOK, 256, 0, stream>>>(ybuf, posl, out);
}

// Round 14
// 490.942 us; speedup vs baseline: 1.4668x; 1.4668x over previous
//
#include <hip/hip_runtime.h>
#include <hip/hip_bf16.h>
#include <math.h>

#define T_TOK 1024
#define H_DIM 2048
#define I_DIM 768
#define E_NUM 32
#define K_TOP 8
#define BK 32
#define GRID_P 1024

typedef __bf16 bf16x8 __attribute__((ext_vector_type(8)));
typedef float  f32x4  __attribute__((ext_vector_type(4)));

__device__ __forceinline__ bf16x8 cvt2_bf16(const f32x4 a, const f32x4 b) {
    bf16x8 r;
    r[0] = (__bf16)a[0]; r[1] = (__bf16)a[1]; r[2] = (__bf16)a[2]; r[3] = (__bf16)a[3];
    r[4] = (__bf16)b[0]; r[5] = (__bf16)b[1]; r[6] = (__bf16)b[2]; r[7] = (__bf16)b[3];
    return r;
}

// LDS fragment-order layout (128 rows x 32 k bf16): element (r,k) at
// (r>>4)*512 + (k>>3)*128 + (r&15)*8 + (k&7). Wave fragment read =
// subtile*512 + lane*8 (16B/lane, linear).
__device__ __forceinline__ int frag_off(int r, int kgrp8) {
    return (r >> 4) * 512 + kgrp8 * 128 + (r & 15) * 8;
}

// ---------------- Router: logits -> top-8 weights; also emits xb (bf16 x) ---
__global__ __launch_bounds__(256) void router_kernel(
    const float* __restrict__ x, const float* __restrict__ gw,
    float* __restrict__ wdense, unsigned int* __restrict__ masks,
    __bf16* __restrict__ xb)
{
    const int t = blockIdx.x;
    const int tid = threadIdx.x;
    __shared__ float part[256];
    __shared__ float logits[E_NUM];

    // fold of cvtx: this block owns row t; write bf16 copy
    {
        const float* xr2 = x + (size_t)t * H_DIM + tid * 8;
        const f32x4 a = *(const f32x4*)(xr2);
        const f32x4 b = *(const f32x4*)(xr2 + 4);
        *(bf16x8*)(xb + (size_t)t * H_DIM + tid * 8) = cvt2_bf16(a, b);
    }

    const int e = tid & 31;
    const int chunk = tid >> 5;
    const float* xr = x + (size_t)t * H_DIM;
    const float* gr = gw + (size_t)e * H_DIM;
    const int base = chunk * (H_DIM / 8);
    float s = 0.f;
    for (int h = 0; h < H_DIM / 8; h += 4) {
        const f32x4 xv = *reinterpret_cast<const f32x4*>(xr + base + h);
        const f32x4 gv = *reinterpret_cast<const f32x4*>(gr + base + h);
        s += xv[0]*gv[0] + xv[1]*gv[1] + xv[2]*gv[2] + xv[3]*gv[3];
    }
    part[tid] = s;
    __syncthreads();
    if (tid < E_NUM) {
        float tot = 0.f;
        for (int c = 0; c < 8; ++c) tot += part[c * 32 + tid];
        logits[tid] = tot;
    }
    __syncthreads();
    if (tid == 0) {
        float l[E_NUM];
        for (int i = 0; i < E_NUM; ++i) {
            l[i] = logits[i];
            wdense[(size_t)t * E_NUM + i] = 0.f;
        }
        unsigned mask = 0;
        int   idx[K_TOP];
        float lv[K_TOP];
        for (int k = 0; k < K_TOP; ++k) {
            float best = -1e30f; int bi = 0;
            for (int i = 0; i < E_NUM; ++i)
                if (!((mask >> i) & 1u) && l[i] > best) { best = l[i]; bi = i; }
            mask |= (1u << bi); idx[k] = bi; lv[k] = best;
        }
        const float m = lv[0];
        float den = 0.f;
        for (int k = 0; k < K_TOP; ++k) den += expf(lv[k] - m);
        for (int k = 0; k < K_TOP; ++k)
            wdense[(size_t)t * E_NUM + idx[k]] = expf(lv[k] - m) / den;
        masks[t] = mask;
    }
}

// ---------------- Build compacted per-expert token lists --------------------
__global__ __launch_bounds__(256) void count_kernel(
    const unsigned int* __restrict__ masks, int* __restrict__ cnt)
{
    const int e = blockIdx.x;
    const int tid = threadIdx.x;
    int c = 0;
    for (int t = tid; t < T_TOK; t += 256) c += (masks[t] >> e) & 1u;
    __shared__ int red[256];
    red[tid] = c; __syncthreads();
    for (int s = 128; s > 0; s >>= 1) {
        if (tid < s) red[tid] += red[tid + s];
        __syncthreads();
    }
    if (tid == 0) cnt[e] = red[0];
}

// scan + live-tile table: tbl[0]=ntiles, tbl[1+i] = (e<<8)|zt  (128-token tiles)
__global__ void scan_kernel(const int* __restrict__ cnt, int* __restrict__ off,
                            int* __restrict__ tbl)
{
    if (threadIdx.x == 0 && blockIdx.x == 0) {
        int r = 0, nt = 0;
        for (int e = 0; e < E_NUM; ++e) {
            off[e] = r;
            const int c = cnt[e];
            r += c;
            const int t = (c + 127) >> 7;
            for (int z = 0; z < t; ++z) tbl[1 + nt++] = (e << 8) | z;
        }
        tbl[0] = nt;
    }
}

// fill: compacted token list + weights + deterministic slot map
// posl[t*8 + slot] = compacted position, slot = #selected experts of t below e.
__global__ __launch_bounds__(256) void fill_kernel(
    const unsigned int* __restrict__ masks, const float* __restrict__ wdense,
    const int* __restrict__ off, int* __restrict__ tok, float* __restrict__ wgt,
    int* __restrict__ posl)
{
    const int e = blockIdx.x;
    const int tid = threadIdx.x;
    const int PER = T_TOK / 256;
    int sel[PER]; int c = 0;
    for (int i = 0; i < PER; ++i) {
        const int t = tid * PER + i;
        sel[i] = (masks[t] >> e) & 1u;
        c += sel[i];
    }
    __shared__ int s[256];
    s[tid] = c; __syncthreads();
    if (tid == 0) {
        int r = 0;
        for (int j = 0; j < 256; ++j) { int v = s[j]; s[j] = r; r += v; }
    }
    __syncthreads();
    int pos = off[e] + s[tid];
    for (int i = 0; i < PER; ++i) {
        if (sel[i]) {
            const int t = tid * PER + i;
            tok[pos] = t;
            wgt[pos] = wdense[(size_t)t * E_NUM + e];
            const int slot = __popc(masks[t] & ((1u << e) - 1u));
            posl[t * K_TOP + slot] = pos;
            pos++;
        }
    }
}

// Depth-3 phase: at step scur reading buf P (write buf Q=P^1):
//  (1) issue loads for step scur+3 into regset I (= scur%3, free since its
//      previous contents went to LDS at phase scur-1);
//  (2) ds_read buf P + 16 MFMA;
//  (3) ds_write regset W (= (scur+1)%3, holds step scur+1, issued 2 phases
//      ago -> ~2 phases of HBM latency hiding) into buf Q;
//  (4) lgkmcnt(0) + raw barrier; 12 loads (2 regsets) stay in flight.
#define GEMM_PHASE(P, Q, I, W)                                                 \
  {                                                                            \
    if (scur + 3 < NS) {                                                       \
      const int kk = (scur + 3) * BK;                                          \
      pa##I##_0 = *(const bf16x8*)(ap + kk);                                   \
      pa##I##_1 = *(const bf16x8*)(ap + kk + 8);                               \
      pb##I##_0 = *(const f32x4*)(wp + kk);                                    \
      pb##I##_1 = *(const f32x4*)(wp + kk + 4);                                \
      pb##I##_2 = *(const f32x4*)(wp + kk + 8);                                \
      pb##I##_3 = *(const f32x4*)(wp + kk + 12);                               \
    }                                                                          \
    bf16x8 af[4], bfr[4];                                                      \
    _Pragma("unroll")                                                          \
    for (int m = 0; m < 4; ++m)                                                \
      af[m] = *(const bf16x8*)&As[P][((wm >> 4) + m) * 512 + lane * 8];        \
    _Pragma("unroll")                                                          \
    for (int n = 0; n < 4; ++n)                                                \
      bfr[n] = *(const bf16x8*)&Bs[P][(wn * 4 + n) * 512 + lane * 8];          \
    _Pragma("unroll")                                                          \
    for (int m = 0; m < 4; ++m)                                                \
      _Pragma("unroll")                                                        \
      for (int n = 0; n < 4; ++n)                                              \
        acc[m][n] = __builtin_amdgcn_mfma_f32_16x16x32_bf16(af[m], bfr[n],     \
                                                            acc[m][n], 0,0,0); \
    if (scur + 1 < NS) {                                                       \
      *(bf16x8*)&As[Q][wo]       = pa##W##_0;                                  \
      *(bf16x8*)&As[Q][wo + 128] = pa##W##_1;                                  \
      *(bf16x8*)&Bs[Q][wo]       = cvt2_bf16(pb##W##_0, pb##W##_1);            \
      *(bf16x8*)&Bs[Q][wo + 128] = cvt2_bf16(pb##W##_2, pb##W##_3);            \
    }                                                                          \
    asm volatile("s_waitcnt lgkmcnt(0)" ::: "memory");                         \
    __builtin_amdgcn_s_barrier();                                              \
    ++scur;                                                                    \
  }

// prologue: issue steps 0,1,2 into R0,R1,R2; write R0 (step 0) -> buf 0.
#define GEMM_PROLOGUE()                                                        \
    pa0_0 = *(const bf16x8*)(ap);                                              \
    pa0_1 = *(const bf16x8*)(ap + 8);                                          \
    pb0_0 = *(const f32x4*)(wp);                                               \
    pb0_1 = *(const f32x4*)(wp + 4);                                           \
    pb0_2 = *(const f32x4*)(wp + 8);                                           \
    pb0_3 = *(const f32x4*)(wp + 12);                                          \
    pa1_0 = *(const bf16x8*)(ap + BK);                                         \
    pa1_1 = *(const bf16x8*)(ap + BK + 8);                                     \
    pb1_0 = *(const f32x4*)(wp + BK);                                          \
    pb1_1 = *(const f32x4*)(wp + BK + 4);                                      \
    pb1_2 = *(const f32x4*)(wp + BK + 8);                                      \
    pb1_3 = *(const f32x4*)(wp + BK + 12);                                     \
    pa2_0 = *(const bf16x8*)(ap + 2 * BK);                                     \
    pa2_1 = *(const bf16x8*)(ap + 2 * BK + 8);                                 \
    pb2_0 = *(const f32x4*)(wp + 2 * BK);                                      \
    pb2_1 = *(const f32x4*)(wp + 2 * BK + 4);                                  \
    pb2_2 = *(const f32x4*)(wp + 2 * BK + 8);                                  \
    pb2_3 = *(const f32x4*)(wp + 2 * BK + 12);                                 \
    *(bf16x8*)&As[0][wo]       = pa0_0;                                        \
    *(bf16x8*)&As[0][wo + 128] = pa0_1;                                        \
    *(bf16x8*)&Bs[0][wo]       = cvt2_bf16(pb0_0, pb0_1);                      \
    *(bf16x8*)&Bs[0][wo + 128] = cvt2_bf16(pb0_2, pb0_3);                      \
    asm volatile("s_waitcnt lgkmcnt(0)" ::: "memory");                         \
    __builtin_amdgcn_s_barrier();

#define GEMM_REGS                                                              \
    bf16x8 pa0_0, pa0_1, pa1_0, pa1_1, pa2_0, pa2_1;                           \
    f32x4  pb0_0, pb0_1, pb0_2, pb0_3;                                         \
    f32x4  pb1_0, pb1_1, pb1_2, pb1_3;                                         \
    f32x4  pb2_0, pb2_1, pb2_2, pb2_3;

#define GEMM_6PHASES()                                                         \
    GEMM_PHASE(0, 1, 0, 1) GEMM_PHASE(1, 0, 1, 2) GEMM_PHASE(0, 1, 2, 0)       \
    GEMM_PHASE(1, 0, 0, 1) GEMM_PHASE(0, 1, 1, 2) GEMM_PHASE(1, 0, 2, 0)

// ---------------- GEMM1: act = silu(x @ w1^T) * (x @ w3^T) ------------------
// Persistent, work w = tile*12 + nidx. Tile: 128 tok x 128 Brows
// ([0:32)=gate lo, [32:64)=up lo, [64:96)=gate hi, [96:128)=up hi).
// Wave (2Mx2N): 64 tok x 64 Brows -> acc[4][4]; n=0,1 gate, n=2,3 up.
// (256,3): ~155 unified regs/wave fits; (256,4) spills (round-13 evidence).
__global__ __launch_bounds__(256, 3) void gemm1_kernel(
    const __bf16* __restrict__ xb, const float* __restrict__ w13,
    const int* __restrict__ tok, const int* __restrict__ cnt,
    const int* __restrict__ off, const int* __restrict__ tbl,
    unsigned short* __restrict__ act)
{
    __shared__ __bf16 As[2][4096];
    __shared__ __bf16 Bs[2][4096];
    const int tid  = threadIdx.x;
    const int wid  = tid >> 6;
    const int lane = tid & 63;
    const int wm = (wid >> 1) * 64;
    const int wn = (wid & 1);
    const int lrow = lane & 15;
    const int sr = tid >> 1;
    const int kh = tid & 1;
    const int wo = frag_off(sr, kh * 2);
    const int NS = H_DIM / BK;   // 64

    const int W = tbl[0] * 12;
    for (int w = blockIdx.x; w < W; w += gridDim.x) {
        const int ti   = w / 12;
        const int nidx = w - ti * 12;
        const int ez = tbl[1 + ti];
        const int e  = ez >> 8;
        const int m0 = (ez & 255) * 128;
        const int c  = cnt[e];
        const int o  = off[e];
        const int n0 = nidx * 64;

        int rA = m0 + sr; rA = rA < c ? rA : c - 1;
        const __bf16* ap = xb + (size_t)tok[o + rA] * H_DIM + kh * 16;
        const int grp = sr >> 5;
        const int wrow = (grp & 1) * I_DIM + n0 + (grp >> 1) * 32 + (sr & 31);
        const float* wp = w13 + (size_t)e * (2 * I_DIM) * H_DIM
                              + (size_t)wrow * H_DIM + kh * 16;

        GEMM_REGS
        f32x4 acc[4][4] = {};

        GEMM_PROLOGUE()

        int scur = 0;
        for (int it = 0; it < 60; it += 6) {
            GEMM_6PHASES()
        }
        // tail: phases 60..63
        GEMM_PHASE(0, 1, 0, 1) GEMM_PHASE(1, 0, 1, 2)
        GEMM_PHASE(0, 1, 2, 0) GEMM_PHASE(1, 0, 0, 1)

        // epilogue: n=0,1 gate, n=2,3 up; icol = n0 + wn*32 + n*16 + lrow
#pragma unroll
        for (int m = 0; m < 4; ++m)
#pragma unroll
            for (int n = 0; n < 2; ++n)
#pragma unroll
                for (int i = 0; i < 4; ++i) {
                    const int row = m0 + wm + m * 16 + (lane >> 4) * 4 + i;
                    if (row < c) {
                        const int icol = n0 + wn * 32 + n * 16 + lrow;
                        const float g = acc[m][n][i];
                        const float u = acc[m][n + 2][i];
                        const float a = (g / (1.f + expf(-g))) * u;
                        act[(size_t)(o + row) * I_DIM + icol] =
                            __builtin_bit_cast(unsigned short, (__bf16)a);
                    }
                }
    }
}

// ---------------- GEMM2: ybuf[o+row] = wgt * (act @ w2^T) (NO atomics) ------
// Persistent, work w = tile*16 + nidx. Tile: 128 tok x 128 H-cols.
__global__ __launch_bounds__(256, 3) void gemm2_kernel(
    const unsigned short* __restrict__ act, const float* __restrict__ w2,
    const int* __restrict__ tok, const float* __restrict__ wgt,
    const int* __restrict__ cnt, const int* __restrict__ off,
    const int* __restrict__ tbl, float* __restrict__ ybuf)
{
    __shared__ __bf16 As[2][4096];
    __shared__ __bf16 Bs[2][4096];
    const int tid  = threadIdx.x;
    const int wid  = tid >> 6;
    const int lane = tid & 63;
    const int wm = (wid >> 1) * 64;
    const int wn = (wid & 1);
    const int lrow = lane & 15;
    const int sr = tid >> 1;
    const int kh = tid & 1;
    const int wo = frag_off(sr, kh * 2);
    const int NS = I_DIM / BK;   // 24

    const int W = tbl[0] * 16;
    for (int w = blockIdx.x; w < W; w += gridDim.x) {
        const int ti   = w >> 4;
        const int nidx = w & 15;
        const int ez = tbl[1 + ti];
        const int e  = ez >> 8;
        const int m0 = (ez & 255) * 128;
        const int c  = cnt[e];
        const int o  = off[e];
        const int n0 = nidx * 128;

        int rA = m0 + sr; rA = rA < c ? rA : c - 1;
        const __bf16* ap = (const __bf16*)act + (size_t)(o + rA) * I_DIM + kh * 16;
        const float* wp = w2 + (size_t)e * H_DIM * I_DIM
                             + (size_t)(n0 + sr) * I_DIM + kh * 16;

        GEMM_REGS
        f32x4 acc[4][4] = {};

        GEMM_PROLOGUE()

        int scur = 0;
        for (int it = 0; it < 24; it += 6) {
            GEMM_6PHASES()
        }

        // epilogue: weighted partial rows, plain coalesced stores (no RMW)
#pragma unroll
        for (int m = 0; m < 4; ++m)
#pragma unroll
            for (int i = 0; i < 4; ++i) {
                const int row = m0 + wm + m * 16 + (lane >> 4) * 4 + i;
                if (row < c) {
                    const float wv = wgt[o + row];
                    float* yr = ybuf + (size_t)(o + row) * H_DIM + n0 + wn * 64 + lrow;
#pragma unroll
                    for (int n = 0; n < 4; ++n)
                        yr[n * 16] = wv * acc[m][n][i];
                }
            }
    }
}

// ---------------- Combine: out[t] = sum_s ybuf[posl[t*8+s]] -----------------
__global__ __launch_bounds__(256) void combine_kernel(
    const float* __restrict__ ybuf, const int* __restrict__ posl,
    float* __restrict__ out)
{
    const int t = blockIdx.x;
    int p[K_TOP];
#pragma unroll
    for (int s = 0; s < K_TOP; ++s) p[s] = posl[t * K_TOP + s];
    const int h0 = threadIdx.x * 4;
#pragma unroll
    for (int hh = h0; hh < H_DIM; hh += 1024) {
        f32x4 a = {0.f, 0.f, 0.f, 0.f};
#pragma unroll
        for (int s = 0; s < K_TOP; ++s) {
            const f32x4 v = *(const f32x4*)(ybuf + (size_t)p[s] * H_DIM + hh);
            a[0] += v[0]; a[1] += v[1]; a[2] += v[2]; a[3] += v[3];
        }
        *(f32x4*)(out + (size_t)t * H_DIM + hh) = a;
    }
}

// ---------------- Launch ----------------------------------------------------
extern "C" void kernel_launch(void* const* d_in, const int* in_sizes, int n_in,
                              void* d_out, int out_size, void* d_ws, size_t ws_size,
                              hipStream_t stream)
{
    const float* x   = (const float*)d_in[0];
    const float* gw  = (const float*)d_in[1];
    const float* w13 = (const float*)d_in[2];
    const float* w2  = (const float*)d_in[3];
    float* out = (float*)d_out;

    char* ws = (char*)d_ws;
    float*          wdense = (float*)(ws + 0x00000);
    unsigned int*   masks  = (unsigned int*)(ws + 0x20000);
    int*            cnt    = (int*)(ws + 0x21000);
    int*            off    = (int*)(ws + 0x21800);
    int*            tbl    = (int*)(ws + 0x22000);
    int*            tok    = (int*)(ws + 0x23000);
    float*          wgt    = (float*)(ws + 0x2B000);
    unsigned short* act    = (unsigned short*)(ws + 0x33000);    // 12.6 MB
    __bf16*         xb     = (__bf16*)(ws + 0xC40000);           // 4 MB
    int*            posl   = (int*)(ws + 0x1040000);             // 32 KB
    float*          ybuf   = (float*)(ws + 0x1100000);           // 67 MB

    router_kernel<<<T_TOK, 256, 0, stream>>>(x, gw, wdense, masks, xb);
    count_kernel<<<E_NUM, 256, 0, stream>>>(masks, cnt);
    scan_kernel<<<1, 64, 0, stream>>>(cnt, off, tbl);
    fill_kernel<<<E_NUM, 256, 0, stream>>>(masks, wdense, off, tok, wgt, posl);
    gemm1_kernel<<<GRID_P, 256, 0, stream>>>(xb, w13, tok, cnt, off, tbl, act);
    gemm2_kernel<<<GRID_P, 256, 0, stream>>>(act, w2, tok, wgt, cnt, off, tbl, ybuf);
    combine_kernel<<<T_TOK, 256, 0, stream>>>(ybuf, posl, out);
}

// Round 15
// 336.764 us; speedup vs baseline: 2.1383x; 1.4578x over previous
//
#include <hip/hip_runtime.h>
#include <hip/hip_bf16.h>
#include <math.h>

#define T_TOK 1024
#define H_DIM 2048
#define I_DIM 768
#define E_NUM 32
#define K_TOP 8
#define BK 32
#define GRID_P 1024

typedef __bf16 bf16x8 __attribute__((ext_vector_type(8)));
typedef float  f32x4  __attribute__((ext_vector_type(4)));

__device__ __forceinline__ bf16x8 cvt2_bf16(const f32x4 a, const f32x4 b) {
    bf16x8 r;
    r[0] = (__bf16)a[0]; r[1] = (__bf16)a[1]; r[2] = (__bf16)a[2]; r[3] = (__bf16)a[3];
    r[4] = (__bf16)b[0]; r[5] = (__bf16)b[1]; r[6] = (__bf16)b[2]; r[7] = (__bf16)b[3];
    return r;
}

// LDS fragment-order layout (128 rows x 32 k bf16): element (r,k) at
// (r>>4)*512 + (k>>3)*128 + (r&15)*8 + (k&7). Wave fragment read =
// subtile*512 + lane*8 (16B/lane, linear).
__device__ __forceinline__ int frag_off(int r, int kgrp8) {
    return (r >> 4) * 512 + kgrp8 * 128 + (r & 15) * 8;
}

// ---------------- Router: logits -> top-8 weights; also emits xb (bf16 x) ---
__global__ __launch_bounds__(256) void router_kernel(
    const float* __restrict__ x, const float* __restrict__ gw,
    float* __restrict__ wdense, unsigned int* __restrict__ masks,
    __bf16* __restrict__ xb)
{
    const int t = blockIdx.x;
    const int tid = threadIdx.x;
    __shared__ float part[256];
    __shared__ float logits[E_NUM];

    // fold of cvtx: this block owns row t; write bf16 copy
    {
        const float* xr2 = x + (size_t)t * H_DIM + tid * 8;
        const f32x4 a = *(const f32x4*)(xr2);
        const f32x4 b = *(const f32x4*)(xr2 + 4);
        *(bf16x8*)(xb + (size_t)t * H_DIM + tid * 8) = cvt2_bf16(a, b);
    }

    const int e = tid & 31;
    const int chunk = tid >> 5;
    const float* xr = x + (size_t)t * H_DIM;
    const float* gr = gw + (size_t)e * H_DIM;
    const int base = chunk * (H_DIM / 8);
    float s = 0.f;
    for (int h = 0; h < H_DIM / 8; h += 4) {
        const f32x4 xv = *reinterpret_cast<const f32x4*>(xr + base + h);
        const f32x4 gv = *reinterpret_cast<const f32x4*>(gr + base + h);
        s += xv[0]*gv[0] + xv[1]*gv[1] + xv[2]*gv[2] + xv[3]*gv[3];
    }
    part[tid] = s;
    __syncthreads();
    if (tid < E_NUM) {
        float tot = 0.f;
        for (int c = 0; c < 8; ++c) tot += part[c * 32 + tid];
        logits[tid] = tot;
    }
    __syncthreads();
    if (tid == 0) {
        float l[E_NUM];
        for (int i = 0; i < E_NUM; ++i) {
            l[i] = logits[i];
            wdense[(size_t)t * E_NUM + i] = 0.f;
        }
        unsigned mask = 0;
        int   idx[K_TOP];
        float lv[K_TOP];
        for (int k = 0; k < K_TOP; ++k) {
            float best = -1e30f; int bi = 0;
            for (int i = 0; i < E_NUM; ++i)
                if (!((mask >> i) & 1u) && l[i] > best) { best = l[i]; bi = i; }
            mask |= (1u << bi); idx[k] = bi; lv[k] = best;
        }
        const float m = lv[0];
        float den = 0.f;
        for (int k = 0; k < K_TOP; ++k) den += expf(lv[k] - m);
        for (int k = 0; k < K_TOP; ++k)
            wdense[(size_t)t * E_NUM + idx[k]] = expf(lv[k] - m) / den;
        masks[t] = mask;
    }
}

// ---------------- Build compacted per-expert token lists --------------------
__global__ __launch_bounds__(256) void count_kernel(
    const unsigned int* __restrict__ masks, int* __restrict__ cnt)
{
    const int e = blockIdx.x;
    const int tid = threadIdx.x;
    int c = 0;
    for (int t = tid; t < T_TOK; t += 256) c += (masks[t] >> e) & 1u;
    __shared__ int red[256];
    red[tid] = c; __syncthreads();
    for (int s = 128; s > 0; s >>= 1) {
        if (tid < s) red[tid] += red[tid + s];
        __syncthreads();
    }
    if (tid == 0) cnt[e] = red[0];
}

// scan + live-tile table: tbl[0]=ntiles, tbl[1+i] = (e<<8)|zt  (128-token tiles)
__global__ void scan_kernel(const int* __restrict__ cnt, int* __restrict__ off,
                            int* __restrict__ tbl)
{
    if (threadIdx.x == 0 && blockIdx.x == 0) {
        int r = 0, nt = 0;
        for (int e = 0; e < E_NUM; ++e) {
            off[e] = r;
            const int c = cnt[e];
            r += c;
            const int t = (c + 127) >> 7;
            for (int z = 0; z < t; ++z) tbl[1 + nt++] = (e << 8) | z;
        }
        tbl[0] = nt;
    }
}

// fill: compacted token list + weights + deterministic slot map
// posl[t*8 + slot] = compacted position, slot = #selected experts of t below e.
__global__ __launch_bounds__(256) void fill_kernel(
    const unsigned int* __restrict__ masks, const float* __restrict__ wdense,
    const int* __restrict__ off, int* __restrict__ tok, float* __restrict__ wgt,
    int* __restrict__ posl)
{
    const int e = blockIdx.x;
    const int tid = threadIdx.x;
    const int PER = T_TOK / 256;
    int sel[PER]; int c = 0;
    for (int i = 0; i < PER; ++i) {
        const int t = tid * PER + i;
        sel[i] = (masks[t] >> e) & 1u;
        c += sel[i];
    }
    __shared__ int s[256];
    s[tid] = c; __syncthreads();
    if (tid == 0) {
        int r = 0;
        for (int j = 0; j < 256; ++j) { int v = s[j]; s[j] = r; r += v; }
    }
    __syncthreads();
    int pos = off[e] + s[tid];
    for (int i = 0; i < PER; ++i) {
        if (sel[i]) {
            const int t = tid * PER + i;
            tok[pos] = t;
            wgt[pos] = wdense[(size_t)t * E_NUM + e];
            const int slot = __popc(masks[t] & ((1u << e) - 1u));
            posl[t * K_TOP + slot] = pos;
            pos++;
        }
    }
}

// Phase macro (round-10 verified anchor): prefetch step scur+2 into regset P,
// MFMA from buf P, write regset Q (=step scur+1) into buf Q. lgkmcnt(0)+raw
// barrier only; global loads stay in flight across the barrier (compiler
// inserts the counted vmcnt before the ds_write that consumes them).
// NOTE: (256,3) is the register-budget optimum — (256,4) spills (r13:
// WRITE 13->586MB), depth-3 spills (r14: WRITE 13->96MB). Do not deepen.
#define GEMM_PHASE(P, Q)                                                       \
  {                                                                            \
    if (scur + 2 < NS) {                                                       \
      const int kk = (scur + 2) * BK;                                          \
      pa##P##_0 = *(const bf16x8*)(ap + kk);                                   \
      pa##P##_1 = *(const bf16x8*)(ap + kk + 8);                               \
      pb##P##_0 = *(const f32x4*)(wp + kk);                                    \
      pb##P##_1 = *(const f32x4*)(wp + kk + 4);                                \
      pb##P##_2 = *(const f32x4*)(wp + kk + 8);                                \
      pb##P##_3 = *(const f32x4*)(wp + kk + 12);                               \
    }                                                                          \
    bf16x8 af[4], bfr[4];                                                      \
    _Pragma("unroll")                                                          \
    for (int m = 0; m < 4; ++m)                                                \
      af[m] = *(const bf16x8*)&As[P][((wm >> 4) + m) * 512 + lane * 8];        \
    _Pragma("unroll")                                                          \
    for (int n = 0; n < 4; ++n)                                                \
      bfr[n] = *(const bf16x8*)&Bs[P][(wn * 4 + n) * 512 + lane * 8];          \
    _Pragma("unroll")                                                          \
    for (int m = 0; m < 4; ++m)                                                \
      _Pragma("unroll")                                                        \
      for (int n = 0; n < 4; ++n)                                              \
        acc[m][n] = __builtin_amdgcn_mfma_f32_16x16x32_bf16(af[m], bfr[n],     \
                                                            acc[m][n], 0,0,0); \
    if (scur + 1 < NS) {                                                       \
      *(bf16x8*)&As[Q][wo]       = pa##Q##_0;                                  \
      *(bf16x8*)&As[Q][wo + 128] = pa##Q##_1;                                  \
      *(bf16x8*)&Bs[Q][wo]       = cvt2_bf16(pb##Q##_0, pb##Q##_1);            \
      *(bf16x8*)&Bs[Q][wo + 128] = cvt2_bf16(pb##Q##_2, pb##Q##_3);            \
    }                                                                          \
    asm volatile("s_waitcnt lgkmcnt(0)" ::: "memory");                         \
    __builtin_amdgcn_s_barrier();                                              \
    ++scur;                                                                    \
  }

#define GEMM_PROLOGUE()                                                        \
    pa0_0 = *(const bf16x8*)(ap);                                              \
    pa0_1 = *(const bf16x8*)(ap + 8);                                          \
    pb0_0 = *(const f32x4*)(wp);                                               \
    pb0_1 = *(const f32x4*)(wp + 4);                                           \
    pb0_2 = *(const f32x4*)(wp + 8);                                           \
    pb0_3 = *(const f32x4*)(wp + 12);                                          \
    pa1_0 = *(const bf16x8*)(ap + BK);                                         \
    pa1_1 = *(const bf16x8*)(ap + BK + 8);                                     \
    pb1_0 = *(const f32x4*)(wp + BK);                                          \
    pb1_1 = *(const f32x4*)(wp + BK + 4);                                      \
    pb1_2 = *(const f32x4*)(wp + BK + 8);                                      \
    pb1_3 = *(const f32x4*)(wp + BK + 12);                                     \
    *(bf16x8*)&As[0][wo]       = pa0_0;                                        \
    *(bf16x8*)&As[0][wo + 128] = pa0_1;                                        \
    *(bf16x8*)&Bs[0][wo]       = cvt2_bf16(pb0_0, pb0_1);                      \
    *(bf16x8*)&Bs[0][wo + 128] = cvt2_bf16(pb0_2, pb0_3);                      \
    asm volatile("s_waitcnt lgkmcnt(0)" ::: "memory");                         \
    __builtin_amdgcn_s_barrier();

// ---------------- GEMM1: act = silu(x @ w1^T) * (x @ w3^T) ------------------
// Persistent, work w = tile*12 + nidx. Tile: 128 tok x 128 Brows
// ([0:32)=gate lo, [32:64)=up lo, [64:96)=gate hi, [96:128)=up hi).
// Wave (2Mx2N): 64 tok x 64 Brows -> acc[4][4]; n=0,1 gate, n=2,3 up.
__global__ __launch_bounds__(256, 3) void gemm1_kernel(
    const __bf16* __restrict__ xb, const float* __restrict__ w13,
    const int* __restrict__ tok, const int* __restrict__ cnt,
    const int* __restrict__ off, const int* __restrict__ tbl,
    unsigned short* __restrict__ act)
{
    __shared__ __bf16 As[2][4096];
    __shared__ __bf16 Bs[2][4096];
    const int tid  = threadIdx.x;
    const int wid  = tid >> 6;
    const int lane = tid & 63;
    const int wm = (wid >> 1) * 64;
    const int wn = (wid & 1);
    const int lrow = lane & 15;
    const int sr = tid >> 1;
    const int kh = tid & 1;
    const int wo = frag_off(sr, kh * 2);
    const int NS = H_DIM / BK;   // 64

    const int W = tbl[0] * 12;
    for (int w = blockIdx.x; w < W; w += gridDim.x) {
        const int ti   = w / 12;
        const int nidx = w - ti * 12;
        const int ez = tbl[1 + ti];
        const int e  = ez >> 8;
        const int m0 = (ez & 255) * 128;
        const int c  = cnt[e];
        const int o  = off[e];
        const int n0 = nidx * 64;

        int rA = m0 + sr; rA = rA < c ? rA : c - 1;
        const __bf16* ap = xb + (size_t)tok[o + rA] * H_DIM + kh * 16;
        const int grp = sr >> 5;
        const int wrow = (grp & 1) * I_DIM + n0 + (grp >> 1) * 32 + (sr & 31);
        const float* wp = w13 + (size_t)e * (2 * I_DIM) * H_DIM
                              + (size_t)wrow * H_DIM + kh * 16;

        bf16x8 pa0_0, pa0_1, pa1_0, pa1_1;
        f32x4  pb0_0, pb0_1, pb0_2, pb0_3, pb1_0, pb1_1, pb1_2, pb1_3;
        f32x4  acc[4][4] = {};

        GEMM_PROLOGUE()

        int scur = 0;
        for (int it = 0; it < NS; it += 2) {
            GEMM_PHASE(0, 1)
            GEMM_PHASE(1, 0)
        }

        // epilogue: n=0,1 gate, n=2,3 up; icol = n0 + wn*32 + n*16 + lrow
#pragma unroll
        for (int m = 0; m < 4; ++m)
#pragma unroll
            for (int n = 0; n < 2; ++n)
#pragma unroll
                for (int i = 0; i < 4; ++i) {
                    const int row = m0 + wm + m * 16 + (lane >> 4) * 4 + i;
                    if (row < c) {
                        const int icol = n0 + wn * 32 + n * 16 + lrow;
                        const float g = acc[m][n][i];
                        const float u = acc[m][n + 2][i];
                        const float a = (g / (1.f + expf(-g))) * u;
                        act[(size_t)(o + row) * I_DIM + icol] =
                            __builtin_bit_cast(unsigned short, (__bf16)a);
                    }
                }
    }
}

// ---------------- GEMM2: ybuf[o+row] = wgt * (act @ w2^T), bf16 partials ----
// Persistent, work w = tile*16 + nidx. Tile: 128 tok x 128 H-cols. No atomics.
__global__ __launch_bounds__(256, 3) void gemm2_kernel(
    const unsigned short* __restrict__ act, const float* __restrict__ w2,
    const int* __restrict__ tok, const float* __restrict__ wgt,
    const int* __restrict__ cnt, const int* __restrict__ off,
    const int* __restrict__ tbl, unsigned short* __restrict__ ybuf)
{
    __shared__ __bf16 As[2][4096];
    __shared__ __bf16 Bs[2][4096];
    const int tid  = threadIdx.x;
    const int wid  = tid >> 6;
    const int lane = tid & 63;
    const int wm = (wid >> 1) * 64;
    const int wn = (wid & 1);
    const int lrow = lane & 15;
    const int sr = tid >> 1;
    const int kh = tid & 1;
    const int wo = frag_off(sr, kh * 2);
    const int NS = I_DIM / BK;   // 24

    const int W = tbl[0] * 16;
    for (int w = blockIdx.x; w < W; w += gridDim.x) {
        const int ti   = w >> 4;
        const int nidx = w & 15;
        const int ez = tbl[1 + ti];
        const int e  = ez >> 8;
        const int m0 = (ez & 255) * 128;
        const int c  = cnt[e];
        const int o  = off[e];
        const int n0 = nidx * 128;

        int rA = m0 + sr; rA = rA < c ? rA : c - 1;
        const __bf16* ap = (const __bf16*)act + (size_t)(o + rA) * I_DIM + kh * 16;
        const float* wp = w2 + (size_t)e * H_DIM * I_DIM
                             + (size_t)(n0 + sr) * I_DIM + kh * 16;

        bf16x8 pa0_0, pa0_1, pa1_0, pa1_1;
        f32x4  pb0_0, pb0_1, pb0_2, pb0_3, pb1_0, pb1_1, pb1_2, pb1_3;
        f32x4  acc[4][4] = {};

        GEMM_PROLOGUE()

        int scur = 0;
        for (int it = 0; it < NS; it += 2) {
            GEMM_PHASE(0, 1)
            GEMM_PHASE(1, 0)
        }

        // epilogue: weighted partial rows, bf16 stores (no RMW)
#pragma unroll
        for (int m = 0; m < 4; ++m)
#pragma unroll
            for (int i = 0; i < 4; ++i) {
                const int row = m0 + wm + m * 16 + (lane >> 4) * 4 + i;
                if (row < c) {
                    const float wv = wgt[o + row];
                    unsigned short* yr = ybuf + (size_t)(o + row) * H_DIM
                                              + n0 + wn * 64 + lrow;
#pragma unroll
                    for (int n = 0; n < 4; ++n)
                        yr[n * 16] = __builtin_bit_cast(
                            unsigned short, (__bf16)(wv * acc[m][n][i]));
                }
            }
    }
}

// ---------------- Combine: out[t] = sum_s ybuf[posl[t*8+s]] (bf16 -> f32) ---
__global__ __launch_bounds__(256) void combine_kernel(
    const unsigned short* __restrict__ ybuf, const int* __restrict__ posl,
    float* __restrict__ out)
{
    const int t = blockIdx.x;
    int p[K_TOP];
#pragma unroll
    for (int s = 0; s < K_TOP; ++s) p[s] = posl[t * K_TOP + s];
    const int h0 = threadIdx.x * 8;          // 256 threads x 8 = 2048 = H_DIM
    float a[8] = {};
#pragma unroll
    for (int s = 0; s < K_TOP; ++s) {
        const bf16x8 v = *(const bf16x8*)(ybuf + (size_t)p[s] * H_DIM + h0);
#pragma unroll
        for (int j = 0; j < 8; ++j) a[j] += (float)v[j];
    }
    f32x4 o0 = {a[0], a[1], a[2], a[3]};
    f32x4 o1 = {a[4], a[5], a[6], a[7]};
    *(f32x4*)(out + (size_t)t * H_DIM + h0)     = o0;
    *(f32x4*)(out + (size_t)t * H_DIM + h0 + 4) = o1;
}

// ---------------- Launch ----------------------------------------------------
extern "C" void kernel_launch(void* const* d_in, const int* in_sizes, int n_in,
                              void* d_out, int out_size, void* d_ws, size_t ws_size,
                              hipStream_t stream)
{
    const float* x   = (const float*)d_in[0];
    const float* gw  = (const float*)d_in[1];
    const float* w13 = (const float*)d_in[2];
    const float* w2  = (const float*)d_in[3];
    float* out = (float*)d_out;

    char* ws = (char*)d_ws;
    float*          wdense = (float*)(ws + 0x00000);
    unsigned int*   masks  = (unsigned int*)(ws + 0x20000);
    int*            cnt    = (int*)(ws + 0x21000);
    int*            off    = (int*)(ws + 0x21800);
    int*            tbl    = (int*)(ws + 0x22000);
    int*            tok    = (int*)(ws + 0x23000);
    float*          wgt    = (float*)(ws + 0x2B000);
    unsigned short* act    = (unsigned short*)(ws + 0x33000);    // 12.6 MB
    __bf16*         xb     = (__bf16*)(ws + 0xC40000);           // 4 MB
    int*            posl   = (int*)(ws + 0x1040000);             // 32 KB
    unsigned short* ybuf   = (unsigned short*)(ws + 0x1100000);  // 33.5 MB

    router_kernel<<<T_TOK, 256, 0, stream>>>(x, gw, wdense, masks, xb);
    count_kernel<<<E_NUM, 256, 0, stream>>>(masks, cnt);
    scan_kernel<<<1, 64, 0, stream>>>(cnt, off, tbl);
    fill_kernel<<<E_NUM, 256, 0, stream>>>(masks, wdense, off, tok, wgt, posl);
    gemm1_kernel<<<GRID_P, 256, 0, stream>>>(xb, w13, tok, cnt, off, tbl, act);
    gemm2_kernel<<<GRID_P, 256, 0, stream>>>(act, w2, tok, wgt, cnt, off, tbl, ybuf);
    combine_kernel<<<T_TOK, 256, 0, stream>>>(ybuf, posl, out);
}